// Round 5
// baseline (281.105 us; speedup 1.0000x reference)
//
#include <hip/hip_runtime.h>
#include <hip/hip_bf16.h>
#include <stdint.h>

// GCN on MI355X. ALL I/O IS FLOAT32.
//   out0 = relu( (D^-1/2 A D^-1/2) @ (graph @ W) + bias )   [16,4096,64] fp32
//   out1 = adj (verbatim fp32 copy)                          [4096,4096] fp32
// Core GEMM: bf16 MFMA, 128x128 tile, BK=32, K-split x4 (grid 1024 = 4 blk/CU)
// with fp32 atomic accumulation; swizzled LDS (kills the 8-way read conflict
// seen in round 4: SQ_LDS_BANK_CONFLICT 4.2M). Scratch 56MB: d_ws if it fits,
// else carved from out1 region (overwritten by the final adj copy).

typedef __bf16 bf16;
typedef __bf16 bf16x8 __attribute__((ext_vector_type(8)));
typedef float f32x4 __attribute__((ext_vector_type(4)));

#define NN 4096
#define BATCH 16
#define FD 64
#define CDIM 1024   // BATCH*FD

// Swizzled LDS chunk index for chunk q (row=q>>2, sub=q&3):
// sub ^= (row>>1)&3  -> per-16-lane-phase bank granule occupancy = 2-way (free).
// Invariant under row += 16, so fragment pointers still step by mi*64.
__device__ __forceinline__ int swz(int q) {
    return (q & ~3) | ((q & 3) ^ ((q >> 3) & 3));
}

// ---------- Kernel 1: adj row -> bf16 + rowsum -> dsq; zero acc; opt. out1 copy ----------
__global__ __launch_bounds__(256) void k_prep(const float* __restrict__ adj,
                                              bf16* __restrict__ adjb,
                                              float* __restrict__ dsq,
                                              float4* __restrict__ acc4,
                                              float4* __restrict__ out1,
                                              int do_copy) {
    int row = blockIdx.x;
    const float4* p = (const float4*)(adj + (size_t)row * NN);  // 1024 x float4
    uint4* q = (uint4*)(adjb + (size_t)row * NN);               // 512 x (8 bf16)
    float4* o = out1 + (size_t)row * (NN / 4);
    float s = 0.f;
    for (int j = threadIdx.x; j < 512; j += 256) {
        float4 a = p[2 * j], b = p[2 * j + 1];
        if (do_copy) { o[2 * j] = a; o[2 * j + 1] = b; }
        bf16x8 h;
        h[0] = (bf16)a.x; h[1] = (bf16)a.y; h[2] = (bf16)a.z; h[3] = (bf16)a.w;
        h[4] = (bf16)b.x; h[5] = (bf16)b.y; h[6] = (bf16)b.z; h[7] = (bf16)b.w;
        q[j] = __builtin_bit_cast(uint4, h);
        s += a.x + a.y + a.z + a.w + b.x + b.y + b.z + b.w;
    }
    // zero this row's slice of the fp32 accumulator (1024 floats = 256 float4)
    acc4[(size_t)row * 256 + threadIdx.x] = (float4){0.f, 0.f, 0.f, 0.f};
    #pragma unroll
    for (int off = 32; off > 0; off >>= 1) s += __shfl_down(s, off, 64);
    __shared__ float red[4];
    int lane = threadIdx.x & 63, wv = threadIdx.x >> 6;
    if (lane == 0) red[wv] = s;
    __syncthreads();
    if (threadIdx.x == 0) {
        float t = red[0] + red[1] + red[2] + red[3];
        if (t == 0.f) t = 1.f;              // isolated-node guard (ref semantics)
        dsq[row] = 1.0f / sqrtf(t);
    }
}

// ---------- Kernel 2: spT[c=b*64+o][m] = dsq[m] * sum_i graph[b,m,i]*W[i,o] ----------
__global__ __launch_bounds__(256) void k_support(const float* __restrict__ graph,
                                                 const float* __restrict__ weight,
                                                 const float* __restrict__ dsq,
                                                 bf16* __restrict__ spT) {
    __shared__ float wT[64 * 64];           // wT[o*64+i]
    int tid = threadIdx.x;
    for (int idx = tid; idx < 4096; idx += 256) {
        int i = idx >> 6, o = idx & 63;
        wT[o * 64 + i] = weight[idx];
    }
    __syncthreads();
    int b = blockIdx.y;
    int m = blockIdx.x * 256 + tid;
    const float4* g4 = (const float4*)(graph + ((size_t)b * NN + m) * FD); // 16 x float4
    float ds = dsq[m];
    float gr[64];
    #pragma unroll
    for (int j = 0; j < 16; j++) {
        float4 v = g4[j];
        gr[4 * j] = v.x * ds; gr[4 * j + 1] = v.y * ds;
        gr[4 * j + 2] = v.z * ds; gr[4 * j + 3] = v.w * ds;
    }
    bf16* outp = spT + m;
    for (int o = 0; o < 64; o++) {
        const float4* w4 = (const float4*)&wT[o * 64];
        float acc = 0.f;
        #pragma unroll
        for (int j = 0; j < 16; j++) {
            float4 wv = w4[j];
            acc += gr[4 * j] * wv.x + gr[4 * j + 1] * wv.y
                 + gr[4 * j + 2] * wv.z + gr[4 * j + 3] * wv.w;
        }
        outp[(size_t)(b * 64 + o) * NN] = (bf16)acc;
    }
}

// ---------- Kernel 3: acc[n][c] += sum_{m in K-chunk} adjb[n][m]*spT[c][m] ----------
// grid (32, 8, 4): z = K-split (chunk of 1024). 128x128 tile, BK=32,
// swizzled LDS, 16x16x32 bf16 MFMA, fp32 atomic accumulate.
__global__ __launch_bounds__(256) void k_gemm(const bf16* __restrict__ adjb,
                                              const bf16* __restrict__ spT,
                                              float* __restrict__ accb) {
    __shared__ uint4 lds_a[512];   // A tile: 128 rows x 32 k (swizzled chunks)
    __shared__ uint4 lds_b[512];   // B tile: 128 c-rows x 32 k
    const int tid = threadIdx.x;
    const int lane = tid & 63;
    const int w = tid >> 6;
    const int n0 = blockIdx.x * 128;
    const int c0 = blockIdx.y * 128;
    const size_t kbase = (size_t)blockIdx.z * (NN / 4);   // 1024-wide K chunk

    const int q0 = tid, q1 = tid + 256;
    const int w0 = swz(q0), w1 = swz(q1);
    const uint4* pA0 = (const uint4*)(adjb + (size_t)(n0 + (q0 >> 2)) * NN + kbase) + (q0 & 3);
    const uint4* pA1 = (const uint4*)(adjb + (size_t)(n0 + (q1 >> 2)) * NN + kbase) + (q1 & 3);
    const uint4* pB0 = (const uint4*)(spT  + (size_t)(c0 + (q0 >> 2)) * NN + kbase) + (q0 & 3);
    const uint4* pB1 = (const uint4*)(spT  + (size_t)(c0 + (q1 >> 2)) * NN + kbase) + (q1 & 3);

    const int r = lane & 15, qo = lane >> 4;
    const int rm = (w >> 1) * 64, rc = (w & 1) * 64;   // 64x64 sub-tile per wave
    const bf16x8* fA = (const bf16x8*)lds_a + (rm + r) * 4 + (qo ^ (((rm + r) >> 1) & 3));
    const bf16x8* fB = (const bf16x8*)lds_b + (rc + r) * 4 + (qo ^ (((rc + r) >> 1) & 3));

    f32x4 ac[4][4];
    #pragma unroll
    for (int i = 0; i < 4; i++)
        #pragma unroll
        for (int j = 0; j < 4; j++)
            ac[i][j] = (f32x4){0.f, 0.f, 0.f, 0.f};

    for (int kt = 0; kt < NN / 4; kt += 32) {
        const int kd = kt >> 3;             // uint4 step (8 bf16 per uint4)
        uint4 va0 = pA0[kd], va1 = pA1[kd];
        uint4 vb0 = pB0[kd], vb1 = pB1[kd];
        __syncthreads();                    // prior iter's reads done
        lds_a[w0] = va0; lds_a[w1] = va1;
        lds_b[w0] = vb0; lds_b[w1] = vb1;
        __syncthreads();                    // tile visible
        bf16x8 af[4], bfr[4];
        #pragma unroll
        for (int mi = 0; mi < 4; mi++) af[mi] = fA[mi * 64];
        #pragma unroll
        for (int ni = 0; ni < 4; ni++) bfr[ni] = fB[ni * 64];
        #pragma unroll
        for (int mi = 0; mi < 4; mi++)
            #pragma unroll
            for (int ni = 0; ni < 4; ni++)
                ac[mi][ni] = __builtin_amdgcn_mfma_f32_16x16x32_bf16(
                    af[mi], bfr[ni], ac[mi][ni], 0, 0, 0);
    }

    // Atomic fp32 accumulate into acc[n][c]
    #pragma unroll
    for (int mi = 0; mi < 4; mi++)
        #pragma unroll
        for (int ni = 0; ni < 4; ni++) {
            int c = c0 + rc + ni * 16 + r;
            #pragma unroll
            for (int rr = 0; rr < 4; rr++) {
                int n = n0 + rm + mi * 16 + qo * 4 + rr;
                unsafeAtomicAdd(&accb[(size_t)n * CDIM + c], ac[mi][ni][rr]);
            }
        }
}

// ---------- Kernel 4: out0[b,n,o] = relu(dsq[n]*acc[n][b*64+o] + bias[o]) ----------
__global__ __launch_bounds__(256) void k_epi(const float4* __restrict__ accv,
                                             const float* __restrict__ dsq,
                                             const float* __restrict__ bias,
                                             float4* __restrict__ out0) {
    int idx = blockIdx.x * 256 + threadIdx.x;       // 1,048,576 float4
    int flat = idx * 4;
    int o4 = flat & 63;
    int n = (flat >> 6) & (NN - 1);
    int b = flat >> 18;                             // 4096*64 = 1<<18
    float4 a = accv[((size_t)n * CDIM + b * 64 + o4) >> 2];
    float d = dsq[n];
    float4 r;
    r.x = fmaxf(a.x * d + bias[o4 + 0], 0.f);
    r.y = fmaxf(a.y * d + bias[o4 + 1], 0.f);
    r.z = fmaxf(a.z * d + bias[o4 + 2], 0.f);
    r.w = fmaxf(a.w * d + bias[o4 + 3], 0.f);
    out0[idx] = r;
}

// ---------- Kernel 5: adj -> out1 fp32 copy (fallback path only, runs LAST) ----------
__global__ __launch_bounds__(256) void k_copy(const float4* __restrict__ src,
                                              float4* __restrict__ dst) {
    size_t i = (size_t)blockIdx.x * 256 + threadIdx.x;
    dst[i] = src[i];
}

extern "C" void kernel_launch(void* const* d_in, const int* in_sizes, int n_in,
                              void* d_out, int out_size, void* d_ws, size_t ws_size,
                              hipStream_t stream) {
    const float *graph = nullptr, *adj = nullptr, *weight = nullptr, *bias = nullptr;
    for (int i = 0; i < n_in; i++) {
        const float* p = (const float*)d_in[i];
        switch (in_sizes[i]) {
            case BATCH * NN * FD: graph  = p; break;   // 4,194,304
            case NN * NN:         adj    = p; break;   // 16,777,216
            case FD * FD:         weight = p; break;   // 4,096
            case FD:              bias   = p; break;   // 64
        }
    }

    float* out0 = (float*)d_out;                       // [16,4096,64] fp32 (16.8MB)
    float* out1 = out0 + (size_t)BATCH * NN * FD;      // [4096,4096] fp32 (67MB)

    // Scratch: adjb 32MB | spT 8MB | dsq 16KB | acc 16.8MB  = ~56MB
    const size_t off_spT = (size_t)NN * NN * 2;
    const size_t off_dsq = off_spT + (size_t)CDIM * NN * 2;
    const size_t off_acc = off_dsq + (size_t)NN * 4;
    const size_t need    = off_acc + (size_t)NN * CDIM * 4;
    const int use_ws = (ws_size >= need);
    char* scratch = use_ws ? (char*)d_ws : (char*)out1;
    bf16*  adjb = (bf16*)scratch;
    bf16*  spT  = (bf16*)(scratch + off_spT);
    float* dsq  = (float*)(scratch + off_dsq);
    float* accb = (float*)(scratch + off_acc);

    hipLaunchKernelGGL(k_prep, dim3(NN), dim3(256), 0, stream,
                       adj, adjb, dsq, (float4*)accb, (float4*)out1, use_ws);
    hipLaunchKernelGGL(k_support, dim3(16, 16), dim3(256), 0, stream,
                       graph, weight, dsq, spT);
    hipLaunchKernelGGL(k_gemm, dim3(32, 8, 4), dim3(256), 0, stream,
                       adjb, spT, accb);
    hipLaunchKernelGGL(k_epi, dim3(4096), dim3(256), 0, stream,
                       (const float4*)accb, dsq, bias, (float4*)out0);
    if (!use_ws) {
        hipLaunchKernelGGL(k_copy, dim3(16384), dim3(256), 0, stream,
                           (const float4*)adj, (float4*)out1);
    }
}

// Round 6
// 243.293 us; speedup vs baseline: 1.1554x; 1.1554x over previous
//
#include <hip/hip_runtime.h>
#include <hip/hip_bf16.h>
#include <stdint.h>

// GCN on MI355X. ALL I/O IS FLOAT32.
//   out0 = relu( (D^-1/2 A D^-1/2) @ (graph @ W) + bias )   [16,4096,64] fp32
//   out1 = adj (verbatim fp32 copy)                          [4096,4096] fp32
// k_gemm: bf16 MFMA 128x128 tile, BK=32, K-split (no atomics -> per-z partial
// fp32 buffers), single-barrier double-buffered LDS pipeline, swizzled LDS
// (round-5: conflicts 4.2M -> 0). dsq row-scale folded into partial store.
// k_epi sums partials + bias + relu.

typedef __bf16 bf16;
typedef __bf16 bf16x8 __attribute__((ext_vector_type(8)));
typedef float f32x4 __attribute__((ext_vector_type(4)));

#define NN 4096
#define BATCH 16
#define FD 64
#define CDIM 1024   // BATCH*FD

// Swizzled LDS chunk index for chunk q (row=q>>2, sub=q&3): sub ^= (row>>1)&3.
__device__ __forceinline__ int swz(int q) {
    return (q & ~3) | ((q & 3) ^ ((q >> 3) & 3));
}

// ---------- Kernel 1: adj -> bf16 + rowsum -> dsq ; optional fused out1 copy ----------
__global__ __launch_bounds__(256) void k_prep(const float* __restrict__ adj,
                                              bf16* __restrict__ adjb,
                                              float* __restrict__ dsq,
                                              float4* __restrict__ out1,
                                              int do_copy) {
    int row = blockIdx.x;
    const float4* p = (const float4*)(adj + (size_t)row * NN);  // 1024 x float4
    uint4* q = (uint4*)(adjb + (size_t)row * NN);               // 512 x (8 bf16)
    float4* o = out1 + (size_t)row * (NN / 4);
    float s = 0.f;
    for (int j = threadIdx.x; j < 512; j += 256) {
        float4 a = p[2 * j], b = p[2 * j + 1];
        if (do_copy) { o[2 * j] = a; o[2 * j + 1] = b; }
        bf16x8 h;
        h[0] = (bf16)a.x; h[1] = (bf16)a.y; h[2] = (bf16)a.z; h[3] = (bf16)a.w;
        h[4] = (bf16)b.x; h[5] = (bf16)b.y; h[6] = (bf16)b.z; h[7] = (bf16)b.w;
        q[j] = __builtin_bit_cast(uint4, h);
        s += a.x + a.y + a.z + a.w + b.x + b.y + b.z + b.w;
    }
    #pragma unroll
    for (int off = 32; off > 0; off >>= 1) s += __shfl_down(s, off, 64);
    __shared__ float red[4];
    int lane = threadIdx.x & 63, wv = threadIdx.x >> 6;
    if (lane == 0) red[wv] = s;
    __syncthreads();
    if (threadIdx.x == 0) {
        float t = red[0] + red[1] + red[2] + red[3];
        if (t == 0.f) t = 1.f;              // isolated-node guard (ref semantics)
        dsq[row] = 1.0f / sqrtf(t);
    }
}

// ---------- Kernel 2: spT[c=b*64+o][m] = dsq[m] * sum_i graph[b,m,i]*W[i,o] ----------
__global__ __launch_bounds__(256) void k_support(const float* __restrict__ graph,
                                                 const float* __restrict__ weight,
                                                 const float* __restrict__ dsq,
                                                 bf16* __restrict__ spT) {
    __shared__ float wT[64 * 64];           // wT[o*64+i]
    int tid = threadIdx.x;
    for (int idx = tid; idx < 4096; idx += 256) {
        int i = idx >> 6, o = idx & 63;
        wT[o * 64 + i] = weight[idx];
    }
    __syncthreads();
    int b = blockIdx.y;
    int m = blockIdx.x * 256 + tid;
    const float4* g4 = (const float4*)(graph + ((size_t)b * NN + m) * FD);
    float ds = dsq[m];
    float gr[64];
    #pragma unroll
    for (int j = 0; j < 16; j++) {
        float4 v = g4[j];
        gr[4 * j] = v.x * ds; gr[4 * j + 1] = v.y * ds;
        gr[4 * j + 2] = v.z * ds; gr[4 * j + 3] = v.w * ds;
    }
    bf16* outp = spT + m;
    for (int o = 0; o < 64; o++) {
        const float4* w4 = (const float4*)&wT[o * 64];
        float acc = 0.f;
        #pragma unroll
        for (int j = 0; j < 16; j++) {
            float4 wv = w4[j];
            acc += gr[4 * j] * wv.x + gr[4 * j + 1] * wv.y
                 + gr[4 * j + 2] * wv.z + gr[4 * j + 3] * wv.w;
        }
        outp[(size_t)(b * 64 + o) * NN] = (bf16)acc;
    }
}

// ---------- Kernel 3: part_z[n][c] = dsq[n] * sum_{m in chunk z} adjb[n][m]*spT[c][m] ----------
// grid (32, 8, nsplit). 128x128 tile, BK=32, double-buffered LDS (1 barrier/iter),
// swizzled chunks, 16x16x32 bf16 MFMA. No atomics.
__global__ __launch_bounds__(256, 4) void k_gemm(const bf16* __restrict__ adjb,
                                                 const bf16* __restrict__ spT,
                                                 const float* __restrict__ dsq,
                                                 float* __restrict__ part,
                                                 int kchunk) {
    __shared__ uint4 lds_a[2][512];   // [buf][chunk]: 128 rows x 32 k, swizzled
    __shared__ uint4 lds_b[2][512];
    const int tid = threadIdx.x;
    const int lane = tid & 63;
    const int w = tid >> 6;
    const int n0 = blockIdx.x * 128;
    const int c0 = blockIdx.y * 128;
    const size_t kbase = (size_t)blockIdx.z * kchunk;
    const int niter = kchunk >> 5;
    float* __restrict__ pp = part + (size_t)blockIdx.z * NN * CDIM;

    const int q0 = tid, q1 = tid + 256;
    const int w0 = swz(q0), w1 = swz(q1);
    const uint4* pA0 = (const uint4*)(adjb + (size_t)(n0 + (q0 >> 2)) * NN + kbase) + (q0 & 3);
    const uint4* pA1 = (const uint4*)(adjb + (size_t)(n0 + (q1 >> 2)) * NN + kbase) + (q1 & 3);
    const uint4* pB0 = (const uint4*)(spT  + (size_t)(c0 + (q0 >> 2)) * NN + kbase) + (q0 & 3);
    const uint4* pB1 = (const uint4*)(spT  + (size_t)(c0 + (q1 >> 2)) * NN + kbase) + (q1 & 3);

    const int r = lane & 15, qo = lane >> 4;
    const int rm = (w >> 1) * 64, rc = (w & 1) * 64;   // 64x64 sub-tile per wave
    const bf16x8* fA = (const bf16x8*)&lds_a[0][0] + (rm + r) * 4 + (qo ^ (((rm + r) >> 1) & 3));
    const bf16x8* fB = (const bf16x8*)&lds_b[0][0] + (rc + r) * 4 + (qo ^ (((rc + r) >> 1) & 3));

    f32x4 ac[4][4];
    #pragma unroll
    for (int i = 0; i < 4; i++)
        #pragma unroll
        for (int j = 0; j < 4; j++)
            ac[i][j] = (f32x4){0.f, 0.f, 0.f, 0.f};

    // Prologue: iter 0 -> buffer 0; prefetch iter 1 into regs.
    uint4 va0 = pA0[0], va1 = pA1[0], vb0 = pB0[0], vb1 = pB1[0];
    lds_a[0][w0] = va0; lds_a[0][w1] = va1;
    lds_b[0][w0] = vb0; lds_b[0][w1] = vb1;
    if (niter > 1) { va0 = pA0[4]; va1 = pA1[4]; vb0 = pB0[4]; vb1 = pB1[4]; }
    __syncthreads();

    for (int kt = 0; kt < niter; kt++) {
        const int cur = kt & 1, nxt = cur ^ 1;
        // LDS -> register fragments (buffer cur)
        bf16x8 af[4], bfr[4];
        const bf16x8* fAc = fA + (cur << 9);
        const bf16x8* fBc = fB + (cur << 9);
        #pragma unroll
        for (int mi = 0; mi < 4; mi++) af[mi] = fAc[mi * 64];
        #pragma unroll
        for (int ni = 0; ni < 4; ni++) bfr[ni] = fBc[ni * 64];
        // Publish iter kt+1 (regs loaded one iter ago), prefetch kt+2
        if (kt + 1 < niter) {
            lds_a[nxt][w0] = va0; lds_a[nxt][w1] = va1;
            lds_b[nxt][w0] = vb0; lds_b[nxt][w1] = vb1;
            if (kt + 2 < niter) {
                const int kd = (kt + 2) * 4;
                va0 = pA0[kd]; va1 = pA1[kd]; vb0 = pB0[kd]; vb1 = pB1[kd];
            }
        }
        __syncthreads();
        #pragma unroll
        for (int mi = 0; mi < 4; mi++)
            #pragma unroll
            for (int ni = 0; ni < 4; ni++)
                ac[mi][ni] = __builtin_amdgcn_mfma_f32_16x16x32_bf16(
                    af[mi], bfr[ni], ac[mi][ni], 0, 0, 0);
    }

    // Store partial with dsq[n] folded in. c = c0+rc+ni*16+r, n = n0+rm+mi*16+qo*4+rr
    #pragma unroll
    for (int mi = 0; mi < 4; mi++) {
        float dn[4];
        #pragma unroll
        for (int rr = 0; rr < 4; rr++) dn[rr] = dsq[n0 + rm + mi * 16 + qo * 4 + rr];
        #pragma unroll
        for (int ni = 0; ni < 4; ni++) {
            int c = c0 + rc + ni * 16 + r;
            #pragma unroll
            for (int rr = 0; rr < 4; rr++) {
                int n = n0 + rm + mi * 16 + qo * 4 + rr;
                pp[(size_t)n * CDIM + c] = dn[rr] * ac[mi][ni][rr];
            }
        }
    }
}

// ---------- Kernel 4: out0[b,n,o] = relu(sum_z part_z[n][b*64+o] + bias[o]) ----------
__global__ __launch_bounds__(256) void k_epi(const float4* __restrict__ part,
                                             int nsplit,
                                             const float* __restrict__ bias,
                                             float4* __restrict__ out0) {
    int idx = blockIdx.x * 256 + threadIdx.x;       // 1,048,576 float4
    int flat = idx * 4;
    int o4 = flat & 63;
    int n = (flat >> 6) & (NN - 1);
    int b = flat >> 18;                             // 4096*64 = 1<<18
    size_t off = ((size_t)n * CDIM + b * 64 + o4) >> 2;
    const size_t zstride = (size_t)NN * CDIM / 4;
    float4 a = part[off];
    for (int z = 1; z < nsplit; z++) {
        float4 t = part[off + z * zstride];
        a.x += t.x; a.y += t.y; a.z += t.z; a.w += t.w;
    }
    float4 bv = *(const float4*)(bias + o4);
    float4 r;
    r.x = fmaxf(a.x + bv.x, 0.f);
    r.y = fmaxf(a.y + bv.y, 0.f);
    r.z = fmaxf(a.z + bv.z, 0.f);
    r.w = fmaxf(a.w + bv.w, 0.f);
    out0[idx] = r;
}

// ---------- Kernel 5: adj -> out1 fp32 copy (fallback path only, runs LAST) ----------
__global__ __launch_bounds__(256) void k_copy(const float4* __restrict__ src,
                                              float4* __restrict__ dst) {
    size_t i = (size_t)blockIdx.x * 256 + threadIdx.x;
    dst[i] = src[i];
}

extern "C" void kernel_launch(void* const* d_in, const int* in_sizes, int n_in,
                              void* d_out, int out_size, void* d_ws, size_t ws_size,
                              hipStream_t stream) {
    const float *graph = nullptr, *adj = nullptr, *weight = nullptr, *bias = nullptr;
    for (int i = 0; i < n_in; i++) {
        const float* p = (const float*)d_in[i];
        switch (in_sizes[i]) {
            case BATCH * NN * FD: graph  = p; break;   // 4,194,304
            case NN * NN:         adj    = p; break;   // 16,777,216
            case FD * FD:         weight = p; break;   // 4,096
            case FD:              bias   = p; break;   // 64
        }
    }

    float* out0 = (float*)d_out;                       // [16,4096,64] fp32 (16.8MB)
    float* out1 = out0 + (size_t)BATCH * NN * FD;      // [4096,4096] fp32 (67MB)

    const size_t SZ_ADJB = (size_t)NN * NN * 2;            // 32 MiB
    const size_t SZ_SPT  = (size_t)CDIM * NN * 2;          // 8 MiB
    const size_t SZ_DSQ  = (size_t)NN * 4;                 // 16 KiB
    const size_t SZ_PART = (size_t)NN * CDIM * 4;          // 16.8 MiB per split

    bf16 *adjb, *spT; float *dsq, *part;
    int nsplit, do_copy_in_prep;
    if (ws_size >= SZ_ADJB + SZ_SPT + SZ_DSQ + 4 * SZ_PART) {
        nsplit = 4; do_copy_in_prep = 1;
        char* s = (char*)d_ws;
        adjb = (bf16*)s;
        spT  = (bf16*)(s + SZ_ADJB);
        dsq  = (float*)(s + SZ_ADJB + SZ_SPT);
        part = (float*)(s + SZ_ADJB + SZ_SPT + SZ_DSQ);
    } else if (ws_size >= SZ_ADJB + SZ_SPT + SZ_DSQ + 2 * SZ_PART) {
        nsplit = 2; do_copy_in_prep = 1;
        char* s = (char*)d_ws;
        adjb = (bf16*)s;
        spT  = (bf16*)(s + SZ_ADJB);
        dsq  = (float*)(s + SZ_ADJB + SZ_SPT);
        part = (float*)(s + SZ_ADJB + SZ_SPT + SZ_DSQ);
    } else {
        // Carve: out1 = [part 2x16.8MB | adjb 32MB] (exactly 64MiB);
        //        out0 = [spT 8MB | dsq 16KB] (consumed before k_epi writes out0).
        nsplit = 2; do_copy_in_prep = 0;
        part = (float*)out1;
        adjb = (bf16*)((char*)out1 + 2 * SZ_PART);
        spT  = (bf16*)out0;
        dsq  = (float*)((char*)out0 + SZ_SPT);
    }
    const int kchunk = NN / nsplit;

    hipLaunchKernelGGL(k_prep, dim3(NN), dim3(256), 0, stream,
                       adj, adjb, dsq, (float4*)out1, do_copy_in_prep);
    hipLaunchKernelGGL(k_support, dim3(16, 16), dim3(256), 0, stream,
                       graph, weight, dsq, spT);
    hipLaunchKernelGGL(k_gemm, dim3(32, 8, nsplit), dim3(256), 0, stream,
                       adjb, spT, dsq, part, kchunk);
    hipLaunchKernelGGL(k_epi, dim3(4096), dim3(256), 0, stream,
                       (const float4*)part, nsplit, bias, (float4*)out0);
    if (!do_copy_in_prep) {
        hipLaunchKernelGGL(k_copy, dim3(16384), dim3(256), 0, stream,
                           (const float4*)adj, (float4*)out1);
    }
}

// Round 7
// 234.735 us; speedup vs baseline: 1.1975x; 1.0365x over previous
//
#include <hip/hip_runtime.h>
#include <hip/hip_bf16.h>
#include <stdint.h>

// GCN on MI355X. ALL I/O IS FLOAT32.
//   out0 = relu( (D^-1/2 A D^-1/2) @ (graph @ W) + bias )   [16,4096,64] fp32
//   out1 = adj (verbatim fp32 copy)                          [4096,4096] fp32
// k_gemm: bf16 MFMA 128x128 tile, BK=32, K-split (per-z bf16 partials, no
// atomics), global_load_lds width=16 staging (no ds_writes, no VGPR round
// trip) with the bank-conflict swizzle applied on the GLOBAL address side
// (LDS writes stay linear as global_load_lds requires; effective layout is
// the round-6 swizzle that measured 0 conflicts). dsq folded into store.

typedef __bf16 bf16;
typedef __bf16 bf16x4 __attribute__((ext_vector_type(4)));
typedef __bf16 bf16x8 __attribute__((ext_vector_type(8)));
typedef float f32x4 __attribute__((ext_vector_type(4)));

#define NN 4096
#define BATCH 16
#define FD 64
#define CDIM 1024   // BATCH*FD

// ---------- Kernel 1: adj -> bf16 + rowsum -> dsq ; optional fused out1 copy ----------
__global__ __launch_bounds__(256) void k_prep(const float* __restrict__ adj,
                                              bf16* __restrict__ adjb,
                                              float* __restrict__ dsq,
                                              float4* __restrict__ out1,
                                              int do_copy) {
    int row = blockIdx.x;
    const float4* p = (const float4*)(adj + (size_t)row * NN);  // 1024 x float4
    uint4* q = (uint4*)(adjb + (size_t)row * NN);               // 512 x (8 bf16)
    float4* o = out1 + (size_t)row * (NN / 4);
    float s = 0.f;
    for (int j = threadIdx.x; j < 512; j += 256) {
        float4 a = p[2 * j], b = p[2 * j + 1];
        if (do_copy) { o[2 * j] = a; o[2 * j + 1] = b; }
        bf16x8 h;
        h[0] = (bf16)a.x; h[1] = (bf16)a.y; h[2] = (bf16)a.z; h[3] = (bf16)a.w;
        h[4] = (bf16)b.x; h[5] = (bf16)b.y; h[6] = (bf16)b.z; h[7] = (bf16)b.w;
        q[j] = __builtin_bit_cast(uint4, h);
        s += a.x + a.y + a.z + a.w + b.x + b.y + b.z + b.w;
    }
    #pragma unroll
    for (int off = 32; off > 0; off >>= 1) s += __shfl_down(s, off, 64);
    __shared__ float red[4];
    int lane = threadIdx.x & 63, wv = threadIdx.x >> 6;
    if (lane == 0) red[wv] = s;
    __syncthreads();
    if (threadIdx.x == 0) {
        float t = red[0] + red[1] + red[2] + red[3];
        if (t == 0.f) t = 1.f;              // isolated-node guard (ref semantics)
        dsq[row] = 1.0f / sqrtf(t);
    }
}

// ---------- Kernel 2: spT[c=b*64+o][m] = dsq[m] * sum_i graph[b,m,i]*W[i,o] ----------
__global__ __launch_bounds__(256) void k_support(const float* __restrict__ graph,
                                                 const float* __restrict__ weight,
                                                 const float* __restrict__ dsq,
                                                 bf16* __restrict__ spT) {
    __shared__ float wT[64 * 64];           // wT[o*64+i]
    int tid = threadIdx.x;
    for (int idx = tid; idx < 4096; idx += 256) {
        int i = idx >> 6, o = idx & 63;
        wT[o * 64 + i] = weight[idx];
    }
    __syncthreads();
    int b = blockIdx.y;
    int m = blockIdx.x * 256 + tid;
    const float4* g4 = (const float4*)(graph + ((size_t)b * NN + m) * FD);
    float ds = dsq[m];
    float gr[64];
    #pragma unroll
    for (int j = 0; j < 16; j++) {
        float4 v = g4[j];
        gr[4 * j] = v.x * ds; gr[4 * j + 1] = v.y * ds;
        gr[4 * j + 2] = v.z * ds; gr[4 * j + 3] = v.w * ds;
    }
    bf16* outp = spT + m;
    for (int o = 0; o < 64; o++) {
        const float4* w4 = (const float4*)&wT[o * 64];
        float acc = 0.f;
        #pragma unroll
        for (int j = 0; j < 16; j++) {
            float4 wv = w4[j];
            acc += gr[4 * j] * wv.x + gr[4 * j + 1] * wv.y
                 + gr[4 * j + 2] * wv.z + gr[4 * j + 3] * wv.w;
        }
        outp[(size_t)(b * 64 + o) * NN] = (bf16)acc;
    }
}

// ---------- Kernel 3: part_z[n][c] = bf16( dsq[n] * sum_{chunk z} adjb[n][m]*spT[c][m] ) ----------
// grid (32, 8, nsplit). 128x128 tile, BK=32, global_load_lds(16B) staging with
// global-side swizzle, 16x16x32 bf16 MFMA.
__global__ __launch_bounds__(256, 4) void k_gemm(const bf16* __restrict__ adjb,
                                                 const bf16* __restrict__ spT,
                                                 const float* __restrict__ dsq,
                                                 bf16* __restrict__ part,
                                                 int kchunk) {
    __shared__ bf16x8 lds_a[512];   // A tile: 128 rows x 32 k; chunk g holds
    __shared__ bf16x8 lds_b[512];   //   (row=g>>2, sub=(g&3)^((g>>3)&3))
    const int tid = threadIdx.x;
    const int lane = tid & 63;
    const int w = tid >> 6;
    const int n0 = blockIdx.x * 128;
    const int c0 = blockIdx.y * 128;
    const size_t kbase = (size_t)blockIdx.z * kchunk;
    const int niter = kchunk >> 5;
    bf16* __restrict__ pp = part + (size_t)blockIdx.z * NN * CDIM;

    // Per-wave staging: 2 A-loads + 2 B-loads, each 64 lanes x 16B = 1KB.
    // LDS write is linear (chunk g = (w*2+j)*64 + lane); the swizzle lives in
    // the per-lane GLOBAL address (sub' = (g&3) ^ ((g>>3)&3)).
    const bf16* gA[2]; const bf16* gB[2];
    bf16x8* lA[2]; bf16x8* lB[2];
    #pragma unroll
    for (int j = 0; j < 2; j++) {
        int g = (w * 2 + j) * 64 + lane;
        int row = g >> 2;
        int sub = (g & 3) ^ ((g >> 3) & 3);
        gA[j] = adjb + (size_t)(n0 + row) * NN + kbase + sub * 8;
        gB[j] = spT  + (size_t)(c0 + row) * NN + kbase + sub * 8;
        lA[j] = &lds_a[(w * 2 + j) * 64];
        lB[j] = &lds_b[(w * 2 + j) * 64];
    }

    const int r = lane & 15, qo = lane >> 4;
    const int rm = (w >> 1) * 64, rc = (w & 1) * 64;   // 64x64 sub-tile per wave
    const bf16x8* fA = lds_a + (rm + r) * 4 + (qo ^ (((rm + r) >> 1) & 3));
    const bf16x8* fB = lds_b + (rc + r) * 4 + (qo ^ (((rc + r) >> 1) & 3));

    f32x4 ac[4][4];
    #pragma unroll
    for (int i = 0; i < 4; i++)
        #pragma unroll
        for (int j = 0; j < 4; j++)
            ac[i][j] = (f32x4){0.f, 0.f, 0.f, 0.f};

    for (int it = 0; it < niter; it++) {
        const int kt = it * 32;
        __syncthreads();                    // prior iter's LDS reads done
        #pragma unroll
        for (int j = 0; j < 2; j++) {
            __builtin_amdgcn_global_load_lds(
                (const __attribute__((address_space(1))) void*)(gA[j] + kt),
                (__attribute__((address_space(3))) void*)lA[j], 16, 0, 0);
            __builtin_amdgcn_global_load_lds(
                (const __attribute__((address_space(1))) void*)(gB[j] + kt),
                (__attribute__((address_space(3))) void*)lB[j], 16, 0, 0);
        }
        __syncthreads();                    // vmcnt drained before barrier
        bf16x8 af[4], bfr[4];
        #pragma unroll
        for (int mi = 0; mi < 4; mi++) af[mi] = fA[mi * 64];
        #pragma unroll
        for (int ni = 0; ni < 4; ni++) bfr[ni] = fB[ni * 64];
        #pragma unroll
        for (int mi = 0; mi < 4; mi++)
            #pragma unroll
            for (int ni = 0; ni < 4; ni++)
                ac[mi][ni] = __builtin_amdgcn_mfma_f32_16x16x32_bf16(
                    af[mi], bfr[ni], ac[mi][ni], 0, 0, 0);
    }

    // Store bf16 partial with dsq[n] folded. c = c0+rc+ni*16+r, n = n0+rm+mi*16+qo*4+rr
    #pragma unroll
    for (int mi = 0; mi < 4; mi++) {
        float dn[4];
        #pragma unroll
        for (int rr = 0; rr < 4; rr++) dn[rr] = dsq[n0 + rm + mi * 16 + qo * 4 + rr];
        #pragma unroll
        for (int ni = 0; ni < 4; ni++) {
            int c = c0 + rc + ni * 16 + r;
            #pragma unroll
            for (int rr = 0; rr < 4; rr++) {
                int n = n0 + rm + mi * 16 + qo * 4 + rr;
                pp[(size_t)n * CDIM + c] = (bf16)(dn[rr] * ac[mi][ni][rr]);
            }
        }
    }
}

// ---------- Kernel 4: out0[b,n,o] = relu(sum_z part_z[n][b*64+o] + bias[o]) ----------
__global__ __launch_bounds__(256) void k_epi(const bf16* __restrict__ part,
                                             int nsplit,
                                             const float* __restrict__ bias,
                                             float4* __restrict__ out0) {
    int idx = blockIdx.x * 256 + threadIdx.x;       // 1,048,576 x (4 floats)
    int flat = idx * 4;
    int o4 = flat & 63;
    int n = (flat >> 6) & (NN - 1);
    int b = flat >> 18;                             // 4096*64 = 1<<18
    size_t off = (size_t)n * CDIM + b * 64 + o4;    // element offset, %4==0
    const size_t zstride = (size_t)NN * CDIM;
    float ax = 0.f, ay = 0.f, az = 0.f, aw = 0.f;
    for (int z = 0; z < nsplit; z++) {
        bf16x4 t = *(const bf16x4*)(part + off + z * zstride);
        ax += (float)t[0]; ay += (float)t[1]; az += (float)t[2]; aw += (float)t[3];
    }
    float4 bv = *(const float4*)(bias + o4);
    float4 r;
    r.x = fmaxf(ax + bv.x, 0.f);
    r.y = fmaxf(ay + bv.y, 0.f);
    r.z = fmaxf(az + bv.z, 0.f);
    r.w = fmaxf(aw + bv.w, 0.f);
    out0[idx] = r;
}

// ---------- Kernel 5: adj -> out1 fp32 copy (fallback path only, runs LAST) ----------
__global__ __launch_bounds__(256) void k_copy(const float4* __restrict__ src,
                                              float4* __restrict__ dst) {
    size_t i = (size_t)blockIdx.x * 256 + threadIdx.x;
    dst[i] = src[i];
}

extern "C" void kernel_launch(void* const* d_in, const int* in_sizes, int n_in,
                              void* d_out, int out_size, void* d_ws, size_t ws_size,
                              hipStream_t stream) {
    const float *graph = nullptr, *adj = nullptr, *weight = nullptr, *bias = nullptr;
    for (int i = 0; i < n_in; i++) {
        const float* p = (const float*)d_in[i];
        switch (in_sizes[i]) {
            case BATCH * NN * FD: graph  = p; break;   // 4,194,304
            case NN * NN:         adj    = p; break;   // 16,777,216
            case FD * FD:         weight = p; break;   // 4,096
            case FD:              bias   = p; break;   // 64
        }
    }

    float* out0 = (float*)d_out;                       // [16,4096,64] fp32 (16.8MB)
    float* out1 = out0 + (size_t)BATCH * NN * FD;      // [4096,4096] fp32 (67MB)

    const size_t SZ_ADJB = (size_t)NN * NN * 2;            // 32 MiB
    const size_t SZ_SPT  = (size_t)CDIM * NN * 2;          // 8 MiB
    const size_t SZ_DSQ  = (size_t)NN * 4;                 // 16 KiB
    const size_t SZ_PART = (size_t)NN * CDIM * 2;          // 8.4 MiB per split (bf16)

    bf16 *adjb, *spT, *part; float *dsq;
    int nsplit, do_copy_in_prep;
    if (ws_size >= SZ_ADJB + SZ_SPT + SZ_DSQ + 4 * SZ_PART) {
        nsplit = 4; do_copy_in_prep = 1;
        char* s = (char*)d_ws;
        adjb = (bf16*)s;
        spT  = (bf16*)(s + SZ_ADJB);
        dsq  = (float*)(s + SZ_ADJB + SZ_SPT);
        part = (bf16*)(s + SZ_ADJB + SZ_SPT + SZ_DSQ);
    } else if (ws_size >= SZ_ADJB + SZ_SPT + SZ_DSQ + 2 * SZ_PART) {
        nsplit = 2; do_copy_in_prep = 1;
        char* s = (char*)d_ws;
        adjb = (bf16*)s;
        spT  = (bf16*)(s + SZ_ADJB);
        dsq  = (float*)(s + SZ_ADJB + SZ_SPT);
        part = (bf16*)(s + SZ_ADJB + SZ_SPT + SZ_DSQ);
    } else {
        // Carve: out1 = [part 4x8.4MB | adjb 32MB] (~66MB of 67MB);
        //        out0 = [spT 8MB | dsq 16KB] (consumed before k_epi writes out0).
        nsplit = 4; do_copy_in_prep = 0;
        part = (bf16*)out1;
        adjb = (bf16*)((char*)out1 + 4 * SZ_PART);
        spT  = (bf16*)out0;
        dsq  = (float*)((char*)out0 + SZ_SPT);
    }
    const int kchunk = NN / nsplit;

    hipLaunchKernelGGL(k_prep, dim3(NN), dim3(256), 0, stream,
                       adj, adjb, dsq, (float4*)out1, do_copy_in_prep);
    hipLaunchKernelGGL(k_support, dim3(16, 16), dim3(256), 0, stream,
                       graph, weight, dsq, spT);
    hipLaunchKernelGGL(k_gemm, dim3(32, 8, nsplit), dim3(256), 0, stream,
                       adjb, spT, dsq, part, kchunk);
    hipLaunchKernelGGL(k_epi, dim3(4096), dim3(256), 0, stream,
                       part, nsplit, bias, (float4*)out0);
    if (!do_copy_in_prep) {
        hipLaunchKernelGGL(k_copy, dim3(16384), dim3(256), 0, stream,
                           (const float4*)adj, (float4*)out1);
    }
}

// Round 8
// 228.508 us; speedup vs baseline: 1.2302x; 1.0273x over previous
//
#include <hip/hip_runtime.h>
#include <hip/hip_bf16.h>
#include <stdint.h>

// GCN on MI355X. ALL I/O IS FLOAT32.
//   out0 = relu( (D^-1/2 A D^-1/2) @ (graph @ W) + bias )   [16,4096,64] fp32
//   out1 = adj (verbatim fp32 copy)                          [4096,4096] fp32
// k_gemm: bf16 MFMA 128x128 tile, BK=64 (halves barrier-drain count vs r7),
// K-split (per-z bf16 partials, no atomics), global_load_lds width=16 staging
// with global-side swizzle sub^=(row&7) -> linear LDS writes, conflict-free
// b128 reads (2 lanes/bank). dsq folded into partial store.

typedef __bf16 bf16;
typedef __bf16 bf16x4 __attribute__((ext_vector_type(4)));
typedef __bf16 bf16x8 __attribute__((ext_vector_type(8)));
typedef float f32x4 __attribute__((ext_vector_type(4)));

#define NN 4096
#define BATCH 16
#define FD 64
#define CDIM 1024   // BATCH*FD

// ---------- Kernel 1: adj -> bf16 + rowsum -> dsq ; optional fused out1 copy ----------
__global__ __launch_bounds__(256) void k_prep(const float* __restrict__ adj,
                                              bf16* __restrict__ adjb,
                                              float* __restrict__ dsq,
                                              float4* __restrict__ out1,
                                              int do_copy) {
    int row = blockIdx.x;
    const float4* p = (const float4*)(adj + (size_t)row * NN);  // 1024 x float4
    uint4* q = (uint4*)(adjb + (size_t)row * NN);               // 512 x (8 bf16)
    float4* o = out1 + (size_t)row * (NN / 4);
    float s = 0.f;
    for (int j = threadIdx.x; j < 512; j += 256) {
        float4 a = p[2 * j], b = p[2 * j + 1];
        if (do_copy) { o[2 * j] = a; o[2 * j + 1] = b; }
        bf16x8 h;
        h[0] = (bf16)a.x; h[1] = (bf16)a.y; h[2] = (bf16)a.z; h[3] = (bf16)a.w;
        h[4] = (bf16)b.x; h[5] = (bf16)b.y; h[6] = (bf16)b.z; h[7] = (bf16)b.w;
        q[j] = __builtin_bit_cast(uint4, h);
        s += a.x + a.y + a.z + a.w + b.x + b.y + b.z + b.w;
    }
    #pragma unroll
    for (int off = 32; off > 0; off >>= 1) s += __shfl_down(s, off, 64);
    __shared__ float red[4];
    int lane = threadIdx.x & 63, wv = threadIdx.x >> 6;
    if (lane == 0) red[wv] = s;
    __syncthreads();
    if (threadIdx.x == 0) {
        float t = red[0] + red[1] + red[2] + red[3];
        if (t == 0.f) t = 1.f;              // isolated-node guard (ref semantics)
        dsq[row] = 1.0f / sqrtf(t);
    }
}

// ---------- Kernel 2: spT[c=b*64+o][m] = dsq[m] * sum_i graph[b,m,i]*W[i,o] ----------
__global__ __launch_bounds__(256) void k_support(const float* __restrict__ graph,
                                                 const float* __restrict__ weight,
                                                 const float* __restrict__ dsq,
                                                 bf16* __restrict__ spT) {
    __shared__ float wT[64 * 64];           // wT[o*64+i]
    int tid = threadIdx.x;
    for (int idx = tid; idx < 4096; idx += 256) {
        int i = idx >> 6, o = idx & 63;
        wT[o * 64 + i] = weight[idx];
    }
    __syncthreads();
    int b = blockIdx.y;
    int m = blockIdx.x * 256 + tid;
    const float4* g4 = (const float4*)(graph + ((size_t)b * NN + m) * FD);
    float ds = dsq[m];
    float gr[64];
    #pragma unroll
    for (int j = 0; j < 16; j++) {
        float4 v = g4[j];
        gr[4 * j] = v.x * ds; gr[4 * j + 1] = v.y * ds;
        gr[4 * j + 2] = v.z * ds; gr[4 * j + 3] = v.w * ds;
    }
    bf16* outp = spT + m;
    for (int o = 0; o < 64; o++) {
        const float4* w4 = (const float4*)&wT[o * 64];
        float acc = 0.f;
        #pragma unroll
        for (int j = 0; j < 16; j++) {
            float4 wv = w4[j];
            acc += gr[4 * j] * wv.x + gr[4 * j + 1] * wv.y
                 + gr[4 * j + 2] * wv.z + gr[4 * j + 3] * wv.w;
        }
        outp[(size_t)(b * 64 + o) * NN] = (bf16)acc;
    }
}

// ---------- Kernel 3: part_z[n][c] = bf16( dsq[n] * sum_{chunk z} adjb[n][m]*spT[c][m] ) ----------
// grid (32, 8, nsplit). 128x128 tile, BK=64, global_load_lds(16B) staging with
// global-side swizzle, 16x16x32 bf16 MFMA, 2 barriers per 64-k step.
__global__ __launch_bounds__(256, 4) void k_gemm(const bf16* __restrict__ adjb,
                                                 const bf16* __restrict__ spT,
                                                 const float* __restrict__ dsq,
                                                 bf16* __restrict__ part,
                                                 int kchunk) {
    __shared__ bf16x8 lds_a[1024];  // A: 128 rows x 64 k; chunk g=(row*8+sub),
    __shared__ bf16x8 lds_b[1024];  //   holds global sub' = sub ^ (row&7)
    const int tid = threadIdx.x;
    const int lane = tid & 63;
    const int w = tid >> 6;
    const int n0 = blockIdx.x * 128;
    const int c0 = blockIdx.y * 128;
    const size_t kbase = (size_t)blockIdx.z * kchunk;
    const int niter = kchunk >> 6;
    bf16* __restrict__ pp = part + (size_t)blockIdx.z * NN * CDIM;

    // Staging: per wave 4 A + 4 B instructions, each 64 lanes x 16B = 1KB.
    // Instruction j covers LDS chunks [(w*4+j)*64, +64); lane supplies the
    // global address of the swizzled sub-chunk that lands at its slot.
    const bf16* gA[4]; const bf16* gB[4];
    bf16x8* lA[4]; bf16x8* lB[4];
    #pragma unroll
    for (int j = 0; j < 4; j++) {
        int g = (w * 4 + j) * 64 + lane;
        int row = g >> 3;
        int sub = (g & 7) ^ (row & 7);      // global-side swizzle
        gA[j] = adjb + (size_t)(n0 + row) * NN + kbase + sub * 8;
        gB[j] = spT  + (size_t)(c0 + row) * NN + kbase + sub * 8;
        lA[j] = &lds_a[(w * 4 + j) * 64];
        lB[j] = &lds_b[(w * 4 + j) * 64];
    }

    const int r = lane & 15, qo = lane >> 4;
    const int rm = (w >> 1) * 64, rc = (w & 1) * 64;   // 64x64 sub-tile per wave
    const int rowA = rm + r, rowB = rc + r;
    // Fragment base for k-half kk: chunk = row*8 + ((kk*4+qo) ^ (row&7));
    // mi/ni step = 16 rows = 128 chunks (XOR term invariant: 16%8==0).
    const bf16x8* fA0 = lds_a + rowA * 8 + ((qo)     ^ (rowA & 7));
    const bf16x8* fA1 = lds_a + rowA * 8 + ((4 + qo) ^ (rowA & 7));
    const bf16x8* fB0 = lds_b + rowB * 8 + ((qo)     ^ (rowB & 7));
    const bf16x8* fB1 = lds_b + rowB * 8 + ((4 + qo) ^ (rowB & 7));

    f32x4 ac[4][4];
    #pragma unroll
    for (int i = 0; i < 4; i++)
        #pragma unroll
        for (int j = 0; j < 4; j++)
            ac[i][j] = (f32x4){0.f, 0.f, 0.f, 0.f};

    for (int it = 0; it < niter; it++) {
        const int kt = it * 64;
        __syncthreads();                    // prior iter's LDS reads done
        #pragma unroll
        for (int j = 0; j < 4; j++) {
            __builtin_amdgcn_global_load_lds(
                (const __attribute__((address_space(1))) void*)(gA[j] + kt),
                (__attribute__((address_space(3))) void*)lA[j], 16, 0, 0);
            __builtin_amdgcn_global_load_lds(
                (const __attribute__((address_space(1))) void*)(gB[j] + kt),
                (__attribute__((address_space(3))) void*)lB[j], 16, 0, 0);
        }
        __syncthreads();                    // vmcnt drained before barrier
        // k-half 0
        {
            bf16x8 af[4], bfr[4];
            #pragma unroll
            for (int mi = 0; mi < 4; mi++) af[mi] = fA0[mi * 128];
            #pragma unroll
            for (int ni = 0; ni < 4; ni++) bfr[ni] = fB0[ni * 128];
            #pragma unroll
            for (int mi = 0; mi < 4; mi++)
                #pragma unroll
                for (int ni = 0; ni < 4; ni++)
                    ac[mi][ni] = __builtin_amdgcn_mfma_f32_16x16x32_bf16(
                        af[mi], bfr[ni], ac[mi][ni], 0, 0, 0);
        }
        // k-half 1
        {
            bf16x8 af[4], bfr[4];
            #pragma unroll
            for (int mi = 0; mi < 4; mi++) af[mi] = fA1[mi * 128];
            #pragma unroll
            for (int ni = 0; ni < 4; ni++) bfr[ni] = fB1[ni * 128];
            #pragma unroll
            for (int mi = 0; mi < 4; mi++)
                #pragma unroll
                for (int ni = 0; ni < 4; ni++)
                    ac[mi][ni] = __builtin_amdgcn_mfma_f32_16x16x32_bf16(
                        af[mi], bfr[ni], ac[mi][ni], 0, 0, 0);
        }
    }

    // Store bf16 partial with dsq[n] folded. c = c0+rc+ni*16+r, n = n0+rm+mi*16+qo*4+rr
    #pragma unroll
    for (int mi = 0; mi < 4; mi++) {
        float dn[4];
        #pragma unroll
        for (int rr = 0; rr < 4; rr++) dn[rr] = dsq[n0 + rm + mi * 16 + qo * 4 + rr];
        #pragma unroll
        for (int ni = 0; ni < 4; ni++) {
            int c = c0 + rc + ni * 16 + r;
            #pragma unroll
            for (int rr = 0; rr < 4; rr++) {
                int n = n0 + rm + mi * 16 + qo * 4 + rr;
                pp[(size_t)n * CDIM + c] = (bf16)(dn[rr] * ac[mi][ni][rr]);
            }
        }
    }
}

// ---------- Kernel 4: out0[b,n,o] = relu(sum_z part_z[n][b*64+o] + bias[o]) ----------
__global__ __launch_bounds__(256) void k_epi(const bf16* __restrict__ part,
                                             int nsplit,
                                             const float* __restrict__ bias,
                                             float4* __restrict__ out0) {
    int idx = blockIdx.x * 256 + threadIdx.x;       // 1,048,576 x (4 floats)
    int flat = idx * 4;
    int o4 = flat & 63;
    int n = (flat >> 6) & (NN - 1);
    int b = flat >> 18;                             // 4096*64 = 1<<18
    size_t off = (size_t)n * CDIM + b * 64 + o4;    // element offset, %4==0
    const size_t zstride = (size_t)NN * CDIM;
    float ax = 0.f, ay = 0.f, az = 0.f, aw = 0.f;
    for (int z = 0; z < nsplit; z++) {
        bf16x4 t = *(const bf16x4*)(part + off + z * zstride);
        ax += (float)t[0]; ay += (float)t[1]; az += (float)t[2]; aw += (float)t[3];
    }
    float4 bv = *(const float4*)(bias + o4);
    float4 r;
    r.x = fmaxf(ax + bv.x, 0.f);
    r.y = fmaxf(ay + bv.y, 0.f);
    r.z = fmaxf(az + bv.z, 0.f);
    r.w = fmaxf(aw + bv.w, 0.f);
    out0[idx] = r;
}

// ---------- Kernel 5: adj -> out1 fp32 copy (fallback path only, runs LAST) ----------
__global__ __launch_bounds__(256) void k_copy(const float4* __restrict__ src,
                                              float4* __restrict__ dst) {
    size_t i = (size_t)blockIdx.x * 256 + threadIdx.x;
    dst[i] = src[i];
}

extern "C" void kernel_launch(void* const* d_in, const int* in_sizes, int n_in,
                              void* d_out, int out_size, void* d_ws, size_t ws_size,
                              hipStream_t stream) {
    const float *graph = nullptr, *adj = nullptr, *weight = nullptr, *bias = nullptr;
    for (int i = 0; i < n_in; i++) {
        const float* p = (const float*)d_in[i];
        switch (in_sizes[i]) {
            case BATCH * NN * FD: graph  = p; break;   // 4,194,304
            case NN * NN:         adj    = p; break;   // 16,777,216
            case FD * FD:         weight = p; break;   // 4,096
            case FD:              bias   = p; break;   // 64
        }
    }

    float* out0 = (float*)d_out;                       // [16,4096,64] fp32 (16.8MB)
    float* out1 = out0 + (size_t)BATCH * NN * FD;      // [4096,4096] fp32 (67MB)

    const size_t SZ_ADJB = (size_t)NN * NN * 2;            // 32 MiB
    const size_t SZ_SPT  = (size_t)CDIM * NN * 2;          // 8 MiB
    const size_t SZ_DSQ  = (size_t)NN * 4;                 // 16 KiB
    const size_t SZ_PART = (size_t)NN * CDIM * 2;          // 8.4 MiB per split (bf16)

    bf16 *adjb, *spT, *part; float *dsq;
    int nsplit, do_copy_in_prep;
    if (ws_size >= SZ_ADJB + SZ_SPT + SZ_DSQ + 4 * SZ_PART) {
        nsplit = 4; do_copy_in_prep = 1;
        char* s = (char*)d_ws;
        adjb = (bf16*)s;
        spT  = (bf16*)(s + SZ_ADJB);
        dsq  = (float*)(s + SZ_ADJB + SZ_SPT);
        part = (bf16*)(s + SZ_ADJB + SZ_SPT + SZ_DSQ);
    } else if (ws_size >= SZ_ADJB + SZ_SPT + SZ_DSQ + 2 * SZ_PART) {
        nsplit = 2; do_copy_in_prep = 1;
        char* s = (char*)d_ws;
        adjb = (bf16*)s;
        spT  = (bf16*)(s + SZ_ADJB);
        dsq  = (float*)(s + SZ_ADJB + SZ_SPT);
        part = (bf16*)(s + SZ_ADJB + SZ_SPT + SZ_DSQ);
    } else {
        // Carve: out1 = [part 4x8.4MB | adjb 32MB] (~66MB of 67MB);
        //        out0 = [spT 8MB | dsq 16KB] (consumed before k_epi writes out0).
        nsplit = 4; do_copy_in_prep = 0;
        part = (bf16*)out1;
        adjb = (bf16*)((char*)out1 + 4 * SZ_PART);
        spT  = (bf16*)out0;
        dsq  = (float*)((char*)out0 + SZ_SPT);
    }
    const int kchunk = NN / nsplit;

    hipLaunchKernelGGL(k_prep, dim3(NN), dim3(256), 0, stream,
                       adj, adjb, dsq, (float4*)out1, do_copy_in_prep);
    hipLaunchKernelGGL(k_support, dim3(16, 16), dim3(256), 0, stream,
                       graph, weight, dsq, spT);
    hipLaunchKernelGGL(k_gemm, dim3(32, 8, nsplit), dim3(256), 0, stream,
                       adjb, spT, dsq, part, kchunk);
    hipLaunchKernelGGL(k_epi, dim3(4096), dim3(256), 0, stream,
                       part, nsplit, bias, (float4*)out0);
    if (!do_copy_in_prep) {
        hipLaunchKernelGGL(k_copy, dim3(16384), dim3(256), 0, stream,
                           (const float4*)adj, (float4*)out1);
    }
}